// Round 5
// baseline (697.005 us; speedup 1.0000x reference)
//
#include <hip/hip_runtime.h>

// Problem constants (match reference).
#define BB 32
#define MM 2048
#define NN 2048
#define ROWS 64      // rows of A per block
#define CHUNKS (MM / ROWS)   // 32 row-chunks per batch
#define HALVES 2             // column halves per row (1024 cols each)
#define THREADS 256  // 4 waves

typedef float f32x4 __attribute__((ext_vector_type(4)));

// ws layout (floats), all written-before-read (no zeroing needed):
//   [0, BB*CHUNKS*NN)            : At_lambda partials, [b][chunk][col]
//   P0 = BB*CHUNKS*NN            : row-dot halves, [b*MM + m]*2 + half
//   P1 = P0 + 2*BB*MM, +FIN*4    : finalize per-block {stat,dual,pr,cm}
#define P0 ((size_t)BB * CHUNKS * NN)
#define P1 (P0 + 2 * (size_t)BB * MM)
#define FIN_BLOCKS 128

__device__ __forceinline__ float waveReduceSum(float v) {
#pragma unroll
    for (int off = 32; off > 0; off >>= 1)
        v += __shfl_down(v, off, 64);
    return v;  // valid in lane 0
}

// DPP row_shr add: pure VALU, no DS pipe. After shr 1,2,4,8 the lane with
// (lane&15)==15 holds the sum of its 16-lane group.
template <int CTRL>
__device__ __forceinline__ float dppAdd(float v) {
    int s = __builtin_amdgcn_update_dpp(0, __builtin_bit_cast(int, v),
                                        CTRL, 0xF, 0xF, false);
    return v + __builtin_bit_cast(float, s);
}

__device__ __forceinline__ float group16Reduce(float v) {
    v = dppAdd<0x111>(v);  // row_shr:1
    v = dppAdd<0x112>(v);  // row_shr:2
    v = dppAdd<0x114>(v);  // row_shr:4
    v = dppAdd<0x118>(v);  // row_shr:8
    return v;              // valid in lane (t&15)==15
}

// Fused pass over A. R5 geometry: BW across R0-R4 tracked resident-wave
// count (16 waves/CU -> 1.8 TB/s; R1's 24-wave spiller -> 3.6 TB/s), not
// per-wave queue depth. So: half-column blocks, ~20 data VGPRs/thread,
// (256,8) -> 8 blocks/CU = 32 waves/CU at zero spill.
// Each block: 64 rows x 1024 cols. Per-row dot half -> ws rowsum half;
// pr/cm/dual math moved to finalize_partial.
__global__ __launch_bounds__(THREADS, 8) void fused_main(
    const float* __restrict__ x_hat, const float* __restrict__ lam_hat,
    const float* __restrict__ A, float* __restrict__ ws) {
    const int b = blockIdx.y;
    const int chunk = blockIdx.x >> 1;
    const int half = blockIdx.x & 1;
    const int m0 = chunk * ROWS;
    const int t = threadIdx.x;

    __shared__ float lamS[ROWS];
    __shared__ __align__(16) float wp[ROWS * 16];

    if (t < ROWS) lamS[t] = lam_hat[b * MM + m0 + t];
    __syncthreads();

    const int RV = NN / 4;        // row stride in f32x4 units (512)
    const int HV = NN / 2 / 4;    // half offset in f32x4 units (256)

    const f32x4* xv = (const f32x4*)(x_hat + (size_t)b * NN) + half * HV;
    const f32x4 x0 = xv[t];

    f32x4 at0 = (f32x4)(0.f);

    const f32x4* Ab =
        (const f32x4*)(A + ((size_t)b * MM + (size_t)m0) * NN) + half * HV;

    // 2-deep rotation: rows r, r+1 live; prefetch r+2 (clamped).
    f32x4 a0 = Ab[t];
    f32x4 a1 = Ab[RV + t];

    for (int r = 0; r < ROWS; ++r) {
        const int rn = (r + 2 < ROWS) ? r + 2 : ROWS - 1;
        f32x4 n = Ab[(size_t)rn * RV + t];

        const float lm = lamS[r];
        f32x4 d = a0 * x0;
        at0 += a0 * lm;
        float dot = (d.x + d.y) + (d.z + d.w);
        dot = group16Reduce(dot);
        if ((t & 15) == 15) wp[r * 16 + (t >> 4)] = dot;

        a0 = a1;
        a1 = n;
    }
    __syncthreads();

    // Wave 0: row t sums its 16 group-partials -> rowsum half to ws.
    if (t < 64) {
        const f32x4* wpv = (const f32x4*)wp;
        f32x4 s4 = wpv[t * 4 + 0] + wpv[t * 4 + 1] +
                   wpv[t * 4 + 2] + wpv[t * 4 + 3];
        float rs = (s4.x + s4.y) + (s4.z + s4.w);
        ws[P0 + ((size_t)b * MM + m0 + t) * 2 + half] = rs;
    }

    // Private-slice flush of the At_lambda partial half (coalesced).
    f32x4* dst =
        (f32x4*)(ws + ((size_t)b * CHUNKS + chunk) * NN) + half * HV;
    dst[t] = at0;
}

// stat: reduce CHUNKS chunk-partials per column. pr/cm/dual: from rowsum
// halves + b_pad + lam. Writes per-block {stat,dual,pr,cm} to ws[P1+..].
__global__ __launch_bounds__(256) void finalize_partial(
    const float* __restrict__ ws_ro, const float* __restrict__ c_pad,
    const float* __restrict__ b_pad, const float* __restrict__ lam_hat,
    float* __restrict__ ws) {
    int idx = blockIdx.x * blockDim.x + threadIdx.x;
    int stride = gridDim.x * blockDim.x;
    float stat = 0.f, dual = 0.f, pr = 0.f, cm = 0.f;
    for (int i = idx; i < BB * NN; i += stride) {
        int b = i >> 11;          // / NN
        int col = i & (NN - 1);
        const float* p = ws_ro + (size_t)b * CHUNKS * NN + col;
        float s = 0.f;
#pragma unroll
        for (int k = 0; k < CHUNKS; ++k) s += p[(size_t)k * NN];
        float v = s + c_pad[i];
        stat += v * v;
    }
    for (int i = idx; i < BB * MM; i += stride) {
        float y = ws_ro[P0 + 2 * (size_t)i] + ws_ro[P0 + 2 * (size_t)i + 1]
                - b_pad[i];
        float l = lam_hat[i];
        float ry = fmaxf(y, 0.f);
        pr += ry * ry;
        float c = l * y;
        cm += c * c;
        float rn = fmaxf(-l, 0.f);
        dual += rn * rn;
    }
    stat = waveReduceSum(stat);
    dual = waveReduceSum(dual);
    pr = waveReduceSum(pr);
    cm = waveReduceSum(cm);
    __shared__ float s[16];
    int wave = threadIdx.x >> 6, lane = threadIdx.x & 63;
    if (lane == 0) {
        s[wave * 4 + 0] = stat; s[wave * 4 + 1] = dual;
        s[wave * 4 + 2] = pr;   s[wave * 4 + 3] = cm;
    }
    __syncthreads();
    if (threadIdx.x < 4) {
        float v = s[threadIdx.x] + s[4 + threadIdx.x] + s[8 + threadIdx.x] + s[12 + threadIdx.x];
        ws[P1 + (size_t)blockIdx.x * 4 + threadIdx.x] = v;
    }
}

// Reduce FIN_BLOCKS x {stat,dual,pr,cm} and apply loss weights.
__global__ __launch_bounds__(256) void combine_kernel(
    const float* __restrict__ ws_ro, float* __restrict__ out) {
    const int t = threadIdx.x;
    const int wave = t >> 6;   // category: 0=stat 1=dual 2=pr 3=cm
    const int lane = t & 63;
    // FIN_BLOCKS == 128: each lane folds two entries.
    float v = ws_ro[P1 + (size_t)lane * 4 + wave]
            + ws_ro[P1 + (size_t)(64 + lane) * 4 + wave];
    v = waveReduceSum(v);
    __shared__ float s[4];
    if (lane == 0) s[wave] = v;
    __syncthreads();
    if (t == 0) {
        const float invBM = 1.0f / (float)(BB * MM);
        const float invBN = 1.0f / (float)(BB * NN);
        float stat = s[0] * invBN;
        float dual = s[1] * invBM;
        float primal = s[2] * invBM;
        float comp = s[3] * invBM;
        out[0] = 0.1f * primal + 0.1f * dual + 0.6f * stat + 0.2f * comp;
    }
}

extern "C" void kernel_launch(void* const* d_in, const int* in_sizes, int n_in,
                              void* d_out, int out_size, void* d_ws, size_t ws_size,
                              hipStream_t stream) {
    const float* x_hat   = (const float*)d_in[0];
    const float* lam_hat = (const float*)d_in[1];
    const float* A       = (const float*)d_in[2];
    const float* b_pad   = (const float*)d_in[3];
    const float* c_pad   = (const float*)d_in[4];
    // d_in[5]/d_in[6] (masks) unused by the reference forward.
    float* out = (float*)d_out;
    float* ws = (float*)d_ws;

    dim3 grid(CHUNKS * HALVES, BB);
    fused_main<<<grid, THREADS, 0, stream>>>(x_hat, lam_hat, A, ws);

    finalize_partial<<<FIN_BLOCKS, 256, 0, stream>>>(ws, c_pad, b_pad, lam_hat, ws);

    combine_kernel<<<1, 256, 0, stream>>>(ws, out);
}

// Round 6
// 665.418 us; speedup vs baseline: 1.0475x; 1.0475x over previous
//
#include <hip/hip_runtime.h>

// Problem constants (match reference).
#define BB 32
#define MM 2048
#define NN 2048
#define ROWS 64      // rows of A per block -> MM/ROWS = 32 chunks per batch
#define CHUNKS (MM / ROWS)
#define THREADS 256  // 4 waves

typedef float f32x4 __attribute__((ext_vector_type(4)));

// ws layout (floats), all written-before-read (no zeroing needed):
//   [0, P0)           : At_lambda partials, [b][chunk][col]   (8 MB)
//   [P0, P0+2048)     : per-fused-block {pr, cm} pairs (BB*CHUNKS = 1024)
//   [P1, P1+512)      : per-finalize-block {stat, dual} pairs (256)
#define P0 ((size_t)BB * CHUNKS * NN)
#define P1 (P0 + 2 * BB * CHUNKS)
#define FIN_BLOCKS 256

__device__ __forceinline__ float waveReduceSum(float v) {
#pragma unroll
    for (int off = 32; off > 0; off >>= 1)
        v += __shfl_down(v, off, 64);
    return v;  // valid in lane 0
}

// DPP row_shr add: pure VALU, no DS pipe. After shr 1,2,4,8 the lane with
// (lane&15)==15 holds the sum of its 16-lane group.
template <int CTRL>
__device__ __forceinline__ float dppAdd(float v) {
    int s = __builtin_amdgcn_update_dpp(0, __builtin_bit_cast(int, v),
                                        CTRL, 0xF, 0xF, false);
    return v + __builtin_bit_cast(float, s);
}

__device__ __forceinline__ float group16Reduce(float v) {
    v = dppAdd<0x111>(v);  // row_shr:1
    v = dppAdd<0x112>(v);  // row_shr:2
    v = dppAdd<0x114>(v);  // row_shr:4
    v = dppAdd<0x118>(v);  // row_shr:8
    return v;              // valid in lane (t&15)==15
}

// fused_main: UNCHANGED from R3 (best measured config: ROWS=64, 1-deep
// prefetch, nontemporal loads, DPP reduce, (256,4)). R4/R5 falsified
// deeper pipelines / higher occupancy as levers for this kernel.
__global__ __launch_bounds__(THREADS, 4) void fused_main(
    const float* __restrict__ x_hat, const float* __restrict__ lam_hat,
    const float* __restrict__ A, const float* __restrict__ b_pad,
    float* __restrict__ ws) {
    const int b = blockIdx.y;
    const int chunk = blockIdx.x;
    const int m0 = chunk * ROWS;
    const int t = threadIdx.x;

    __shared__ float lamS[ROWS];
    __shared__ __align__(16) float wp[ROWS * 16];

    if (t < ROWS) lamS[t] = lam_hat[b * MM + m0 + t];
    __syncthreads();

    const f32x4* xv = (const f32x4*)(x_hat + (size_t)b * NN);
    const f32x4 x0 = xv[t];
    const f32x4 x1 = xv[256 + t];

    f32x4 at0 = (f32x4)(0.f);
    f32x4 at1 = (f32x4)(0.f);

    const f32x4* Ab = (const f32x4*)(A + ((size_t)b * MM + (size_t)m0) * NN);

    f32x4 a0 = __builtin_nontemporal_load(Ab + t);
    f32x4 a1 = __builtin_nontemporal_load(Ab + 256 + t);

#define ROW_BODY(r)                                              \
    do {                                                         \
        const float lm = lamS[r];                                \
        f32x4 d = a0 * x0 + a1 * x1;                             \
        at0 += a0 * lm;                                          \
        at1 += a1 * lm;                                          \
        float dot = (d.x + d.y) + (d.z + d.w);                   \
        dot = group16Reduce(dot);                                \
        if ((t & 15) == 15) wp[(r) * 16 + (t >> 4)] = dot;       \
    } while (0)

    for (int r = 0; r < ROWS - 1; ++r) {
        const f32x4* np = Ab + (size_t)(r + 1) * (NN / 4);
        f32x4 n0 = __builtin_nontemporal_load(np + t);
        f32x4 n1 = __builtin_nontemporal_load(np + 256 + t);

        ROW_BODY(r);

        a0 = n0;
        a1 = n1;
    }
    ROW_BODY(ROWS - 1);
#undef ROW_BODY
    __syncthreads();

    if (t < 64) {
        const f32x4* wpv = (const f32x4*)wp;
        f32x4 s4 = wpv[t * 4 + 0] + wpv[t * 4 + 1] +
                   wpv[t * 4 + 2] + wpv[t * 4 + 3];
        float y = (s4.x + s4.y) + (s4.z + s4.w) - b_pad[b * MM + m0 + t];
        float lm = lamS[t];
        float ry = fmaxf(y, 0.f);
        float pr = ry * ry;
        float c = lm * y;
        float cm = c * c;
        pr = waveReduceSum(pr);
        cm = waveReduceSum(cm);
        if (t == 0) {
            float* prcm = ws + P0 + ((size_t)b * CHUNKS + chunk) * 2;
            prcm[0] = pr;
            prcm[1] = cm;
        }
    }

    f32x4* dst = (f32x4*)(ws + ((size_t)b * CHUNKS + chunk) * NN);
    dst[t] = at0;
    dst[256 + t] = at1;
}

// finalize_partial, rebuilt for latency (R1-probe: old version cost
// ~100-210 us for ~24 MB of L3-resident traffic -- 0.5 block/CU, scalar
// 4B loads, 32-deep serial column walks).
// New mapping: 256 blocks (1/CU). Block = (b, colgroup of 256 floats).
// Thread = (colvec c in [0,64), k-quarter kq in [0,4)): 8 independent
// f32x4 loads, LDS combine of the 4 k-quarters, vectorized dual fold.
__global__ __launch_bounds__(256) void finalize_partial(
    const float* __restrict__ ws_ro, const float* __restrict__ c_pad,
    const float* __restrict__ lam_hat, float* __restrict__ ws) {
    const int t = threadIdx.x;
    const int b = blockIdx.x >> 3;        // 32 batches
    const int g = blockIdx.x & 7;         // 8 col-groups of 256 floats
    const int c = t & 63;                 // f32x4 colvec within group
    const int kq = t >> 6;                // k-quarter (0..3)

    // Partial surface as f32x4: row stride per chunk = NN/4 = 512.
    const f32x4* base = (const f32x4*)ws_ro +
        ((size_t)b * CHUNKS + (size_t)kq * 8) * (NN / 4) + (size_t)g * 64 + c;
    f32x4 s = (f32x4)(0.f);
#pragma unroll
    for (int k = 0; k < 8; ++k) s += base[(size_t)k * (NN / 4)];

    __shared__ __align__(16) f32x4 part[4][64];
    part[kq][c] = s;
    __syncthreads();

    float stat = 0.f, dual = 0.f;
    if (t < 64) {
        f32x4 v = part[0][c] + part[1][c] + part[2][c] + part[3][c];
        f32x4 cp = ((const f32x4*)c_pad)[(size_t)b * (NN / 4) + (size_t)g * 64 + c];
        v += cp;
        stat = v.x * v.x + v.y * v.y + v.z * v.z + v.w * v.w;

        // dual: lam slice for this block (BB*MM/4 = 16384 f32x4 over 256 blocks).
        f32x4 l = ((const f32x4*)lam_hat)[(size_t)blockIdx.x * 64 + c];
        float r0 = fmaxf(-l.x, 0.f), r1 = fmaxf(-l.y, 0.f);
        float r2 = fmaxf(-l.z, 0.f), r3 = fmaxf(-l.w, 0.f);
        dual = r0 * r0 + r1 * r1 + r2 * r2 + r3 * r3;

        stat = waveReduceSum(stat);
        dual = waveReduceSum(dual);
        if (t == 0) {
            ws[P1 + (size_t)blockIdx.x * 2 + 0] = stat;
            ws[P1 + (size_t)blockIdx.x * 2 + 1] = dual;
        }
    }
}

// combine: reduce 256 {stat,dual} pairs (P1) and 1024 {pr,cm} pairs (P0),
// apply loss weights. One block, 4 waves: one category per wave.
__global__ __launch_bounds__(256) void combine_kernel(
    const float* __restrict__ ws_ro, float* __restrict__ out) {
    const int t = threadIdx.x;
    const int wave = t >> 6;   // 0=stat 1=dual 2=pr 3=cm
    const int lane = t & 63;
    float v = 0.f;
    if (wave == 0) {
#pragma unroll
        for (int j = 0; j < 4; ++j)
            v += ws_ro[P1 + (size_t)((lane << 2) | j) * 2 + 0];
    } else if (wave == 1) {
#pragma unroll
        for (int j = 0; j < 4; ++j)
            v += ws_ro[P1 + (size_t)((lane << 2) | j) * 2 + 1];
    } else if (wave == 2) {
#pragma unroll
        for (int j = 0; j < 16; ++j)
            v += ws_ro[P0 + (size_t)((lane << 4) | j) * 2 + 0];
    } else {
#pragma unroll
        for (int j = 0; j < 16; ++j)
            v += ws_ro[P0 + (size_t)((lane << 4) | j) * 2 + 1];
    }
    v = waveReduceSum(v);
    __shared__ float s[4];
    if (lane == 0) s[wave] = v;
    __syncthreads();
    if (t == 0) {
        const float invBM = 1.0f / (float)(BB * MM);
        const float invBN = 1.0f / (float)(BB * NN);
        float stat = s[0] * invBN;
        float dual = s[1] * invBM;
        float primal = s[2] * invBM;
        float comp = s[3] * invBM;
        out[0] = 0.1f * primal + 0.1f * dual + 0.6f * stat + 0.2f * comp;
    }
}

extern "C" void kernel_launch(void* const* d_in, const int* in_sizes, int n_in,
                              void* d_out, int out_size, void* d_ws, size_t ws_size,
                              hipStream_t stream) {
    const float* x_hat   = (const float*)d_in[0];
    const float* lam_hat = (const float*)d_in[1];
    const float* A       = (const float*)d_in[2];
    const float* b_pad   = (const float*)d_in[3];
    const float* c_pad   = (const float*)d_in[4];
    // d_in[5]/d_in[6] (masks) unused by the reference forward.
    float* out = (float*)d_out;
    float* ws = (float*)d_ws;

    dim3 grid(CHUNKS, BB);
    fused_main<<<grid, THREADS, 0, stream>>>(x_hat, lam_hat, A, b_pad, ws);

    finalize_partial<<<FIN_BLOCKS, 256, 0, stream>>>(ws, c_pad, lam_hat, ws);

    combine_kernel<<<1, 256, 0, stream>>>(ws, out);
}

// Round 7
// 662.787 us; speedup vs baseline: 1.0516x; 1.0040x over previous
//
#include <hip/hip_runtime.h>

// Problem constants (match reference).
#define BB 32
#define MM 2048
#define NN 2048
#define ROWS 64      // rows of A per block -> MM/ROWS = 32 chunks per batch
#define CHUNKS (MM / ROWS)
#define THREADS 256  // 4 waves

typedef float f32x4 __attribute__((ext_vector_type(4)));

// ws layout (floats), all written-before-read (no zeroing needed):
//   [0, P0)           : At_lambda partials, [b][chunk][col]   (8 MB)
//   [P0, P0+2048)     : per-fused-block {pr, cm} pairs (BB*CHUNKS = 1024)
//   [P1, P1+512)      : per-finalize-block {stat, dual} pairs (256)
#define P0 ((size_t)BB * CHUNKS * NN)
#define P1 (P0 + 2 * BB * CHUNKS)
#define FIN_BLOCKS 256

__device__ __forceinline__ float waveReduceSum(float v) {
#pragma unroll
    for (int off = 32; off > 0; off >>= 1)
        v += __shfl_down(v, off, 64);
    return v;  // valid in lane 0
}

// DPP row_shr add: pure VALU, no DS pipe. After shr 1,2,4,8 the lane with
// (lane&15)==15 holds the sum of its 16-lane group.
template <int CTRL>
__device__ __forceinline__ float dppAdd(float v) {
    int s = __builtin_amdgcn_update_dpp(0, __builtin_bit_cast(int, v),
                                        CTRL, 0xF, 0xF, false);
    return v + __builtin_bit_cast(float, s);
}

__device__ __forceinline__ float group16Reduce(float v) {
    v = dppAdd<0x111>(v);  // row_shr:1
    v = dppAdd<0x112>(v);  // row_shr:2
    v = dppAdd<0x114>(v);  // row_shr:4
    v = dppAdd<0x118>(v);  // row_shr:8
    return v;              // valid in lane (t&15)==15
}

// fused_main: R3 structure + per-block row-phase stagger.
// Theory (R7): all blocks sit at the same row phase r at any instant, and
// block bases are =0 mod 512KB, so chip-wide concurrent requests occupy one
// 8KB window of the channel-interleave period -> ~1/4 of HBM/L2 channels
// active -> observed 1.8 TB/s (=25% of achievable). Staggering each block's
// starting row by r0=(g*37)&63 spreads instantaneous traffic over 64 row
// offsets -> all channels busy. (R1's phase-spread spill traffic hit 3.6 TB/s
// in this same kernel -- the chip can do it.)
__global__ __launch_bounds__(THREADS, 4) void fused_main(
    const float* __restrict__ x_hat, const float* __restrict__ lam_hat,
    const float* __restrict__ A, const float* __restrict__ b_pad,
    float* __restrict__ ws) {
    const int b = blockIdx.y;
    const int chunk = blockIdx.x;
    const int m0 = chunk * ROWS;
    const int t = threadIdx.x;
    const int r0 = ((b * CHUNKS + chunk) * 37) & (ROWS - 1);

    __shared__ float lamS[ROWS];
    __shared__ __align__(16) float wp[ROWS * 16];

    if (t < ROWS) lamS[t] = lam_hat[b * MM + m0 + t];
    __syncthreads();

    const f32x4* xv = (const f32x4*)(x_hat + (size_t)b * NN);
    const f32x4 x0 = xv[t];
    const f32x4 x1 = xv[256 + t];

    f32x4 at0 = (f32x4)(0.f);
    f32x4 at1 = (f32x4)(0.f);

    const f32x4* Ab = (const f32x4*)(A + ((size_t)b * MM + (size_t)m0) * NN);

    // Prologue: row r0 in flight.
    int rr = r0;
    f32x4 a0 = __builtin_nontemporal_load(Ab + (size_t)rr * (NN / 4) + t);
    f32x4 a1 = __builtin_nontemporal_load(Ab + (size_t)rr * (NN / 4) + 256 + t);

#define ROW_BODY(RI)                                             \
    do {                                                         \
        const float lm = lamS[RI];                               \
        f32x4 d = a0 * x0 + a1 * x1;                             \
        at0 += a0 * lm;                                          \
        at1 += a1 * lm;                                          \
        float dot = (d.x + d.y) + (d.z + d.w);                   \
        dot = group16Reduce(dot);                                \
        if ((t & 15) == 15) wp[(RI) * 16 + (t >> 4)] = dot;      \
    } while (0)

    for (int r = 0; r < ROWS - 1; ++r) {
        // Prefetch next row (wrapped) while computing on the current one.
        const int rn = (rr + 1) & (ROWS - 1);
        const f32x4* np = Ab + (size_t)rn * (NN / 4);
        f32x4 n0 = __builtin_nontemporal_load(np + t);
        f32x4 n1 = __builtin_nontemporal_load(np + 256 + t);

        ROW_BODY(rr);

        a0 = n0;
        a1 = n1;
        rr = rn;
    }
    ROW_BODY(rr);  // peeled: no clamped re-load of the last row
#undef ROW_BODY
    __syncthreads();

    // Wave 0 finalizes: row t sums its 16 group-partials, then wave-wide
    // pr/cm reduce across the 64 rows.
    if (t < 64) {
        const f32x4* wpv = (const f32x4*)wp;
        f32x4 s4 = wpv[t * 4 + 0] + wpv[t * 4 + 1] +
                   wpv[t * 4 + 2] + wpv[t * 4 + 3];
        float y = (s4.x + s4.y) + (s4.z + s4.w) - b_pad[b * MM + m0 + t];
        float lm = lamS[t];
        float ry = fmaxf(y, 0.f);
        float pr = ry * ry;
        float c = lm * y;
        float cm = c * c;
        pr = waveReduceSum(pr);
        cm = waveReduceSum(cm);
        if (t == 0) {
            float* prcm = ws + P0 + ((size_t)b * CHUNKS + chunk) * 2;
            prcm[0] = pr;
            prcm[1] = cm;
        }
    }

    // Private-slice flush of the At_lambda partial (coalesced, no atomics).
    f32x4* dst = (f32x4*)(ws + ((size_t)b * CHUNKS + chunk) * NN);
    dst[t] = at0;
    dst[256 + t] = at1;
}

// finalize_partial (R6 version): 256 blocks (1/CU). Block = (b, colgroup of
// 256 floats). Thread = (colvec c in [0,64), k-quarter kq in [0,4)): 8
// independent f32x4 loads, LDS combine of the 4 k-quarters, vectorized dual.
__global__ __launch_bounds__(256) void finalize_partial(
    const float* __restrict__ ws_ro, const float* __restrict__ c_pad,
    const float* __restrict__ lam_hat, float* __restrict__ ws) {
    const int t = threadIdx.x;
    const int b = blockIdx.x >> 3;        // 32 batches
    const int g = blockIdx.x & 7;         // 8 col-groups of 256 floats
    const int c = t & 63;                 // f32x4 colvec within group
    const int kq = t >> 6;                // k-quarter (0..3)

    const f32x4* base = (const f32x4*)ws_ro +
        ((size_t)b * CHUNKS + (size_t)kq * 8) * (NN / 4) + (size_t)g * 64 + c;
    f32x4 s = (f32x4)(0.f);
#pragma unroll
    for (int k = 0; k < 8; ++k) s += base[(size_t)k * (NN / 4)];

    __shared__ __align__(16) f32x4 part[4][64];
    part[kq][c] = s;
    __syncthreads();

    float stat = 0.f, dual = 0.f;
    if (t < 64) {
        f32x4 v = part[0][c] + part[1][c] + part[2][c] + part[3][c];
        f32x4 cp = ((const f32x4*)c_pad)[(size_t)b * (NN / 4) + (size_t)g * 64 + c];
        v += cp;
        stat = v.x * v.x + v.y * v.y + v.z * v.z + v.w * v.w;

        f32x4 l = ((const f32x4*)lam_hat)[(size_t)blockIdx.x * 64 + c];
        float r0 = fmaxf(-l.x, 0.f), r1 = fmaxf(-l.y, 0.f);
        float r2 = fmaxf(-l.z, 0.f), r3 = fmaxf(-l.w, 0.f);
        dual = r0 * r0 + r1 * r1 + r2 * r2 + r3 * r3;

        stat = waveReduceSum(stat);
        dual = waveReduceSum(dual);
        if (t == 0) {
            ws[P1 + (size_t)blockIdx.x * 2 + 0] = stat;
            ws[P1 + (size_t)blockIdx.x * 2 + 1] = dual;
        }
    }
}

// combine: reduce 256 {stat,dual} pairs (P1) and 1024 {pr,cm} pairs (P0),
// apply loss weights. One block, 4 waves: one category per wave.
__global__ __launch_bounds__(256) void combine_kernel(
    const float* __restrict__ ws_ro, float* __restrict__ out) {
    const int t = threadIdx.x;
    const int wave = t >> 6;   // 0=stat 1=dual 2=pr 3=cm
    const int lane = t & 63;
    float v = 0.f;
    if (wave == 0) {
#pragma unroll
        for (int j = 0; j < 4; ++j)
            v += ws_ro[P1 + (size_t)((lane << 2) | j) * 2 + 0];
    } else if (wave == 1) {
#pragma unroll
        for (int j = 0; j < 4; ++j)
            v += ws_ro[P1 + (size_t)((lane << 2) | j) * 2 + 1];
    } else if (wave == 2) {
#pragma unroll
        for (int j = 0; j < 16; ++j)
            v += ws_ro[P0 + (size_t)((lane << 4) | j) * 2 + 0];
    } else {
#pragma unroll
        for (int j = 0; j < 16; ++j)
            v += ws_ro[P0 + (size_t)((lane << 4) | j) * 2 + 1];
    }
    v = waveReduceSum(v);
    __shared__ float s[4];
    if (lane == 0) s[wave] = v;
    __syncthreads();
    if (t == 0) {
        const float invBM = 1.0f / (float)(BB * MM);
        const float invBN = 1.0f / (float)(BB * NN);
        float stat = s[0] * invBN;
        float dual = s[1] * invBM;
        float primal = s[2] * invBM;
        float comp = s[3] * invBM;
        out[0] = 0.1f * primal + 0.1f * dual + 0.6f * stat + 0.2f * comp;
    }
}

extern "C" void kernel_launch(void* const* d_in, const int* in_sizes, int n_in,
                              void* d_out, int out_size, void* d_ws, size_t ws_size,
                              hipStream_t stream) {
    const float* x_hat   = (const float*)d_in[0];
    const float* lam_hat = (const float*)d_in[1];
    const float* A       = (const float*)d_in[2];
    const float* b_pad   = (const float*)d_in[3];
    const float* c_pad   = (const float*)d_in[4];
    // d_in[5]/d_in[6] (masks) unused by the reference forward.
    float* out = (float*)d_out;
    float* ws = (float*)d_ws;

    dim3 grid(CHUNKS, BB);
    fused_main<<<grid, THREADS, 0, stream>>>(x_hat, lam_hat, A, b_pad, ws);

    finalize_partial<<<FIN_BLOCKS, 256, 0, stream>>>(ws, c_pad, lam_hat, ws);

    combine_kernel<<<1, 256, 0, stream>>>(ws, out);
}